// Round 14
// baseline (570.273 us; speedup 1.0000x reference)
//
#include <hip/hip_runtime.h>
#include <hip/hip_bf16.h>

// Problem constants (fixed by the reference: N=50000, E=400000, D=128, H=256, L=5)
#define NNODES 50000
#define MPAD 50048          // 782 * 64 (gemm row padding)
#define NEDGES 400000
#define DIM 128
#define HID 256
#define NLAYERS 5
#define BONDSZ 13
#define NCOMBO 60           // 5*6*2 bond-attr combinations
#define BN_EPS 1e-5f
#define NCHUNK 49           // ceil(50000/1024)
#define INVN (1.0f / 50000.0f)

typedef __bf16 bf16x8 __attribute__((ext_vector_type(8)));
typedef __bf16 bf16x4v __attribute__((ext_vector_type(4)));
typedef float f32x4 __attribute__((ext_vector_type(4)));

// Inline-asm 16B global load: cannot be sunk by regalloc; dest stays live
// from issue to use. "memory" clobber orders C++ stores after it, which the
// persistent-loop vmcnt accounting relies on.
#define GLOAD16(dst, addr) \
    asm volatile("global_load_dwordx4 %0, %1, off" : "=v"(dst) : "v"(addr) : "memory")

// Counted wait (T4): never drain vmcnt to 0 in the stripe loop.
// DEPTH=2: wait vmcnt(16) = loads(t+1..) not yet issued; 16 newest =
//   stores(t-1); guarantees loads(t) retired.
// DEPTH=3: wait vmcnt(32) AFTER issuing A(t+2): 32 newest = loads(t+1) 8
//   + loads(t+2) 8 + stores(t-1) 16; loads(t) older -> retired.
template<int N> __device__ __forceinline__ void vmwaitN() {
    if constexpr (N == 16)      asm volatile("s_waitcnt vmcnt(16)" ::: "memory");
    else if constexpr (N == 32) asm volatile("s_waitcnt vmcnt(32)" ::: "memory");
    else static_assert(N == 16 || N == 32, "unsupported vmcnt");
    __builtin_amdgcn_sched_barrier(0);
}

// ===========================================================================
// CSR build (once per call — edge topology is layer-invariant)
// ===========================================================================
__global__ __launch_bounds__(256) void hist_kernel(
    const int* __restrict__ dst, int* __restrict__ deg)
{
    int e = blockIdx.x * 256 + threadIdx.x;
    if (e < NEDGES) atomicAdd(&deg[dst[e]], 1);
}

__global__ __launch_bounds__(256) void scan_sum(
    const int* __restrict__ deg, int* __restrict__ partial)
{
    __shared__ int red[256];
    int base = blockIdx.x * 1024;
    int s = 0;
    for (int i = threadIdx.x; i < 1024; i += 256) {
        int idx = base + i;
        if (idx < NNODES) s += deg[idx];
    }
    red[threadIdx.x] = s;
    __syncthreads();
    for (int off = 128; off > 0; off >>= 1) {
        if (threadIdx.x < off) red[threadIdx.x] += red[threadIdx.x + off];
        __syncthreads();
    }
    if (threadIdx.x == 0) partial[blockIdx.x] = red[0];
}

__global__ void scan_part(int* __restrict__ partial, int n, int* __restrict__ rowptr_last)
{
    if (threadIdx.x == 0) {
        int acc = 0;
        for (int i = 0; i < n; i++) { int v = partial[i]; partial[i] = acc; acc += v; }
        rowptr_last[0] = acc;
    }
}

__global__ __launch_bounds__(256) void scan_write(
    const int* __restrict__ deg, const int* __restrict__ partial,
    int* __restrict__ row_ptr)
{
    __shared__ int red[256];
    int base = blockIdx.x * 1024;
    int t = threadIdx.x;
    int v[4];
    int s = 0;
    #pragma unroll
    for (int j = 0; j < 4; j++) {
        int idx = base + t * 4 + j;
        v[j] = (idx < NNODES) ? deg[idx] : 0;
        s += v[j];
    }
    red[t] = s;
    __syncthreads();
    for (int off = 1; off < 256; off <<= 1) {
        int x = (t >= off) ? red[t - off] : 0;
        __syncthreads();
        red[t] += x;
        __syncthreads();
    }
    int ex = red[t] - s + partial[blockIdx.x];
    #pragma unroll
    for (int j = 0; j < 4; j++) {
        int idx = base + t * 4 + j;
        if (idx < NNODES) row_ptr[idx] = ex;
        ex += v[j];
    }
}

// packed edge: (src << 6) | combo  (src < 2^17, combo < 60)
__global__ __launch_bounds__(256) void scatter_kernel(
    const int* __restrict__ src, const int* __restrict__ dst,
    const int* __restrict__ eattr, const int* __restrict__ row_ptr,
    int* __restrict__ cursor, int* __restrict__ epack)
{
    int e = blockIdx.x * 256 + threadIdx.x;
    if (e >= NEDGES) return;
    int d = dst[e];
    int pos = row_ptr[d] + atomicAdd(&cursor[d], 1);
    int a0 = eattr[e * 3 + 0];
    int a1 = eattr[e * 3 + 1];
    int a2 = eattr[e * 3 + 2];
    epack[pos] = (src[e] << 6) | (a0 * 12 + a1 * 2 + a2);
}

// ===========================================================================
// Weight pre-split (once): W -> transposed [n][k] bf16 hi/lo planes
// ===========================================================================
__global__ __launch_bounds__(256) void wsplit_kernel(
    const float* __restrict__ W1, const float* __restrict__ W2,
    __bf16* __restrict__ bt1h, __bf16* __restrict__ bt1l,
    __bf16* __restrict__ bt2h, __bf16* __restrict__ bt2l)
{
    int gid = blockIdx.x * 256 + threadIdx.x;
    const int total1 = NLAYERS * DIM * HID;
    if (gid < total1) {
        int n = gid % HID; int k = (gid / HID) % DIM; int l = gid / (DIM * HID);
        float w = W1[gid];
        __bf16 hi = (__bf16)w;
        int o = (l * HID + n) * DIM + k;
        bt1h[o] = hi; bt1l[o] = (__bf16)(w - (float)hi);
    } else {
        int g = gid - total1;
        if (g < NLAYERS * HID * DIM) {
            int n = g % DIM; int k = (g / DIM) % HID; int l = g / (HID * DIM);
            float w = W2[g];
            __bf16 hi = (__bf16)w;
            int o = (l * DIM + n) * HID + k;
            bt2h[o] = hi; bt2l[o] = (__bf16)(w - (float)hi);
        }
    }
}

// ===========================================================================
// Aggregation + GIN combine (CSR, zero atomics).
//   Round 14: packed int edges (halved epack stream). Structure otherwise
//   round-13 (4-deep pipeline, bf16 gather+self plane for TRANS=1).
//   agg is at its structural floor: FETCH 99.8MB = 8 XCDs x ~12.5MB
//   compulsory random-gather plane replication; dur 44.6-45.1us invariant
//   across 14 rounds of ILP/occupancy/precision changes.
// ===========================================================================
template<int TRANS>
__global__ __launch_bounds__(1024) void agg_combine(
    const float* __restrict__ hin,
    const __bf16* __restrict__ hb,
    const int* __restrict__ row_ptr, const int* __restrict__ epack,
    const float* __restrict__ bond,
    const float* __restrict__ epsv, int lidx,
    const float* __restrict__ csIn, const float* __restrict__ cqIn,
    const float* __restrict__ gamma, const float* __restrict__ beta,
    __bf16* __restrict__ zH, __bf16* __restrict__ zL,
    float* __restrict__ statsZero)
{
    __shared__ float T[BONDSZ * DIM];
    __shared__ float TC[NCOMBO * DIM];
    __shared__ float scs[DIM], shs[DIM];

    for (int i = threadIdx.x; i < BONDSZ * DIM; i += 1024) T[i] = bond[i];
    if (TRANS && threadIdx.x < DIM) {
        int c = threadIdx.x;
        float mu = csIn[c] * INVN;
        float var = cqIn[c] * INVN - mu * mu;
        float sv = gamma[c] * rsqrtf(var + BN_EPS);
        scs[c] = sv; shs[c] = beta[c] - mu * sv;
    }
    if (blockIdx.x == 0 && threadIdx.x < 768) statsZero[threadIdx.x] = 0.f;
    __syncthreads();
    // build combined table: TC[cb] = T[a0] + T[5+a1] + T[11+a2]
    for (int i = threadIdx.x; i < NCOMBO * DIM; i += 1024) {
        int cb = i >> 7, c = i & 127;
        int a0 = cb / 12, r = cb - a0 * 12;
        TC[i] = T[a0 * DIM + c] + T[(5 + (r >> 1)) * DIM + c] + T[(11 + (r & 1)) * DIM + c];
    }
    __syncthreads();

    const int wv = threadIdx.x >> 6;            // 0..15
    const int half = (threadIdx.x >> 5) & 1;
    const int li = threadIdx.x & 31;
    const int node = blockIdx.x * 32 + wv * 2 + half;
    if (node >= NNODES) return;
    const int f = li * 4;

    float4 sc4 = make_float4(1.f, 1.f, 1.f, 1.f);
    float4 sh4 = make_float4(0.f, 0.f, 0.f, 0.f);
    if (TRANS) { sc4 = *(const float4*)&scs[f]; sh4 = *(const float4*)&shs[f]; }

    float ax = 0.f, ay = 0.f, az = 0.f, aw = 0.f;
    const int s = row_ptr[node];
    const int e2 = row_ptr[node + 1];
    int i = s;
    // ---- 4-deep pipelined main loop
    for (; i + 3 < e2; i += 4) {
        int ev[4];
        ev[0] = epack[i];     ev[1] = epack[i + 1];
        ev[2] = epack[i + 2]; ev[3] = epack[i + 3];
        float4 gv[4], tv[4];
        #pragma unroll
        for (int u = 0; u < 4; u++) {
            if (TRANS) {
                bf16x4v gb = *(const bf16x4v*)&hb[(size_t)(ev[u] >> 6) * DIM + f];
                gv[u] = make_float4((float)gb[0], (float)gb[1], (float)gb[2], (float)gb[3]);
            } else {
                gv[u] = *(const float4*)&hin[(size_t)(ev[u] >> 6) * DIM + f];
            }
            tv[u] = *(const float4*)&TC[(ev[u] & 63) * DIM + f];
        }
        #pragma unroll
        for (int u = 0; u < 4; u++) {
            float4 g = gv[u], t = tv[u];
            if (TRANS) {
                g.x = fmaxf(g.x * sc4.x + sh4.x, 0.f); g.y = fmaxf(g.y * sc4.y + sh4.y, 0.f);
                g.z = fmaxf(g.z * sc4.z + sh4.z, 0.f); g.w = fmaxf(g.w * sc4.w + sh4.w, 0.f);
            }
            ax += fmaxf(g.x + t.x, 0.f);
            ay += fmaxf(g.y + t.y, 0.f);
            az += fmaxf(g.z + t.z, 0.f);
            aw += fmaxf(g.w + t.w, 0.f);
        }
    }
    // ---- tail (<=3 edges)
    for (; i < e2; i++) {
        int ev = epack[i];
        float4 g;
        if (TRANS) {
            bf16x4v gb = *(const bf16x4v*)&hb[(size_t)(ev >> 6) * DIM + f];
            g = make_float4((float)gb[0], (float)gb[1], (float)gb[2], (float)gb[3]);
        } else {
            g = *(const float4*)&hin[(size_t)(ev >> 6) * DIM + f];
        }
        float4 t = *(const float4*)&TC[(ev & 63) * DIM + f];
        if (TRANS) {
            g.x = fmaxf(g.x * sc4.x + sh4.x, 0.f); g.y = fmaxf(g.y * sc4.y + sh4.y, 0.f);
            g.z = fmaxf(g.z * sc4.z + sh4.z, 0.f); g.w = fmaxf(g.w * sc4.w + sh4.w, 0.f);
        }
        ax += fmaxf(g.x + t.x, 0.f);
        ay += fmaxf(g.y + t.y, 0.f);
        az += fmaxf(g.z + t.z, 0.f);
        aw += fmaxf(g.w + t.w, 0.f);
    }
    // ---- self term (bf16 plane for TRANS=1 — same class as messages)
    float4 hv;
    if (TRANS) {
        bf16x4v hbv = *(const bf16x4v*)&hb[(size_t)node * DIM + f];
        hv = make_float4((float)hbv[0], (float)hbv[1], (float)hbv[2], (float)hbv[3]);
        hv.x = fmaxf(hv.x * sc4.x + sh4.x, 0.f); hv.y = fmaxf(hv.y * sc4.y + sh4.y, 0.f);
        hv.z = fmaxf(hv.z * sc4.z + sh4.z, 0.f); hv.w = fmaxf(hv.w * sc4.w + sh4.w, 0.f);
    } else {
        hv = *(const float4*)&hin[(size_t)node * DIM + f];
    }
    float ep = 1.0f + epsv[lidx];
    float z0 = ep * hv.x + ax, z1 = ep * hv.y + ay;
    float z2 = ep * hv.z + az, z3 = ep * hv.w + aw;
    __bf16 h0 = (__bf16)z0, h1 = (__bf16)z1, h2 = (__bf16)z2, h3 = (__bf16)z3;
    size_t o = (size_t)node * DIM + f;
    bf16x4v vh = {h0, h1, h2, h3};
    bf16x4v vl = {(__bf16)(z0 - (float)h0), (__bf16)(z1 - (float)h1),
                  (__bf16)(z2 - (float)h2), (__bf16)(z3 - (float)h3)};
    *(bf16x4v*)(zH + o) = vh;
    *(bf16x4v*)(zL + o) = vl;
}

// ===========================================================================
// PERSISTENT-STRIPE split-precision MFMA GEMM (round 14).
//   Structure: B staged once; stripe t+1's asm loads in flight across
//   stripe t's compute; stats in registers with one block reduce through
//   dead sBH; XCD stripe pairing. All outputs bf16 (y2 fp32 eliminated —
//   bn_out now reads the bf16 plane).
//   DEPTH=3 (gemm2): prefetch ring 3-deep — with ~3 stripes/block all A
//   loads are issued by end of stripe 0; consume-wait vmcnt(32) =
//   loads(t+1) 8 + loads(t+2) 8 + stores(t-1) 16 (derivation in vmwaitN).
//   DEPTH=2 (gemm1): wait vmcnt(16) as rounds 11-13.
//   gemm1: K=128, COLS=64, XB=4, TRANSFORM=0, DEPTH=2.
//   gemm2: K=256, COLS=64, XB=2, TRANSFORM=1, DEPTH=3 (pB[3][8]=96 VGPR).
// ===========================================================================
template<int K, int NCOLS, int COLS, int TRANSFORM, int XB, int MINW, int DEPTH>
__global__ __launch_bounds__(256, MINW) void gemm_ps(
    const __bf16* __restrict__ AH, const __bf16* __restrict__ AL,
    const __bf16* __restrict__ AB,
    const __bf16* __restrict__ BTH, const __bf16* __restrict__ BTL,
    const float* __restrict__ bias,
    const float* __restrict__ csIn, const float* __restrict__ cqIn,
    const float* __restrict__ gamma, const float* __restrict__ beta,
    __bf16* __restrict__ outB,
    float* __restrict__ colsum, float* __restrict__ colsumsq)
{
    constexpr int KC  = K / 8;          // 16B chunks per col
    constexpr int NK  = K / 32;         // ksteps (gemm1 4, gemm2 8)
    constexpr int NJ  = COLS / 16;      // col sub-blocks per wave
    constexpr int NYB = MPAD / 64;      // 782 row-stripes of 64
    constexpr int WC  = (DEPTH == 3) ? 32 : 16;   // consume-wait count

    __shared__ __bf16 sBH[COLS * K], sBL[COLS * K];
    __shared__ float scs[TRANSFORM ? K : 1], shs[TRANSFORM ? K : 1];

    const int bid  = blockIdx.x;
    const int xcd  = bid & 7;
    const int grp  = bid >> 3;
    const int xb   = grp % XB;                      // column block
    const int pb   = (grp / XB) * 8 + xcd;          // stripe base 0..255
    const int tid  = threadIdx.x;
    const int lane = tid & 63;
    const int wv   = tid >> 6;
    const int rowL = lane & 15;
    const int quad = lane >> 4;
    const int n0   = xb * COLS;

    // A prefetch ring (depth DEPTH), stripe t uses buf t%DEPTH
    bf16x8 pH[DEPTH][TRANSFORM ? 1 : NK], pL[DEPTH][TRANSFORM ? 1 : NK];
    bf16x8 pB[DEPTH][TRANSFORM ? NK : 1];

#define A_ISSUE(tt) do {                                                      \
    const size_t rb_ = ((size_t)(pb + 256 * (tt)) * 64 + wv * 16 + rowL) * K  \
                       + quad * 8;                                            \
    _Pragma("unroll")                                                         \
    for (int ks = 0; ks < NK; ks++) {                                         \
        if constexpr (!TRANSFORM) {                                           \
            GLOAD16(pH[(tt) % DEPTH][ks], AH + rb_ + ks * 32);                \
            GLOAD16(pL[(tt) % DEPTH][ks], AL + rb_ + ks * 32);                \
        } else {                                                              \
            GLOAD16(pB[(tt) % DEPTH][ks], AB + rb_ + ks * 32);                \
        }                                                                     \
    }                                                                         \
} while (0)

    // prologue loads overlap the B staging phase (drained at the barrier)
    A_ISSUE(0);
    if constexpr (DEPTH == 3) {
        if (pb + 256 < NYB) A_ISSUE(1);
    }

    // per-block constants (keep ALL C++ global loads out of the stripe loop)
    float bb[NJ];
    #pragma unroll
    for (int j = 0; j < NJ; j++) bb[j] = bias[n0 + j * 16 + rowL];
    if (TRANSFORM) {
        for (int c = tid; c < K; c += 256) {
            float mu = csIn[c] * INVN;
            float var = cqIn[c] * INVN - mu * mu;
            float sv = gamma[c] * rsqrtf(var + BN_EPS);
            scs[c] = sv; shs[c] = beta[c] - mu * sv;
        }
    }

    // ---- stage B once (both planes, swizzled chunk layout)
    #pragma unroll
    for (int it = 0; it < (COLS * KC) / 256; it++) {
        int c = it * 256 + tid;
        int col = c / KC, kq = c % KC;
        int slot = col * KC + (kq ^ (col & (KC - 1)));
        size_t g = (size_t)(n0 + col) * K + kq * 8;
        *(bf16x8*)(sBH + slot * 8) = *(const bf16x8*)(BTH + g);
        *(bf16x8*)(sBL + slot * 8) = *(const bf16x8*)(BTL + g);
    }
    __syncthreads();                      // drains vmcnt incl. prologue loads
    __builtin_amdgcn_sched_barrier(0);

    // per-column stats accumulated in registers across stripes
    float stS[NJ] = {}, stQ[NJ] = {};

#define STRIPE(tt) do {                                                       \
    if (pb + 256 * (tt) < NYB) {                                              \
        if constexpr (DEPTH == 3 && (tt) + 2 <= 3) {                          \
            if (pb + 256 * ((tt) + 2) < NYB) A_ISSUE((tt) + 2);               \
        }                                                                     \
        if constexpr ((tt) > 0) { vmwaitN<WC>(); }                            \
        if constexpr (DEPTH == 2 && (tt) + 1 <= 3) {                          \
            if (pb + 256 * ((tt) + 1) < NYB) A_ISSUE((tt) + 1);               \
        }                                                                     \
        f32x4 acc[NJ] = {};                                                   \
        _Pragma("unroll")                                                     \
        for (int ks = 0; ks < NK; ks++) {                                     \
            bf16x8 aH8, aL8;                                                  \
            if constexpr (!TRANSFORM) {                                       \
                aH8 = pH[(tt) % DEPTH][ks];                                   \
                aL8 = pL[(tt) % DEPTH][ks];                                   \
            } else {                                                          \
                const int kb = ks * 32 + quad * 8;                            \
                float4 s0 = *(const float4*)&scs[kb];                         \
                float4 s1 = *(const float4*)&scs[kb + 4];                     \
                float4 t0 = *(const float4*)&shs[kb];                         \
                float4 t1 = *(const float4*)&shs[kb + 4];                     \
                float sv[8] = {s0.x, s0.y, s0.z, s0.w, s1.x, s1.y, s1.z, s1.w}; \
                float tv[8] = {t0.x, t0.y, t0.z, t0.w, t1.x, t1.y, t1.z, t1.w}; \
                _Pragma("unroll")                                             \
                for (int e = 0; e < 8; e++) {                                 \
                    float v = fmaxf((float)pB[(tt) % DEPTH][ks][e] * sv[e] + tv[e], 0.f); \
                    __bf16 hi = (__bf16)v;                                    \
                    aH8[e] = hi;                                              \
                    aL8[e] = (__bf16)(v - (float)hi);                         \
                }                                                             \
            }                                                                 \
            const int kqr = ks * 4 + quad;                                    \
            _Pragma("unroll")                                                 \
            for (int j = 0; j < NJ; j++) {                                    \
                int col = j * 16 + rowL;                                      \
                int slot = col * KC + (kqr ^ (col & (KC - 1)));               \
                bf16x8 bH = *(const bf16x8*)(sBH + slot * 8);                 \
                bf16x8 bL = *(const bf16x8*)(sBL + slot * 8);                 \
                acc[j] = __builtin_amdgcn_mfma_f32_16x16x32_bf16(aH8, bH, acc[j], 0, 0, 0); \
                acc[j] = __builtin_amdgcn_mfma_f32_16x16x32_bf16(aL8, bH, acc[j], 0, 0, 0); \
                acc[j] = __builtin_amdgcn_mfma_f32_16x16x32_bf16(aH8, bL, acc[j], 0, 0, 0); \
            }                                                                 \
        }                                                                     \
        /* epilogue: exactly 16 unconditional bf16 stores (vmcnt accounting) */ \
        const int r0t = (pb + 256 * (tt)) * 64 + wv * 16 + quad * 4;          \
        _Pragma("unroll")                                                     \
        for (int j = 0; j < NJ; j++) {                                        \
            const int colL = j * 16 + rowL;                                   \
            _Pragma("unroll")                                                 \
            for (int r = 0; r < 4; r++) {                                     \
                const int rr = r0t + r;                                       \
                float v = acc[j][r] + bb[j];                                  \
                outB[(size_t)rr * NCOLS + n0 + colL] = (__bf16)v;             \
                if (rr < NNODES) { stS[j] += v; stQ[j] += v * v; }            \
            }                                                                 \
        }                                                                     \
    }                                                                         \
} while (0)

    STRIPE(0);
    STRIPE(1);
    STRIPE(2);
    STRIPE(3);

#undef STRIPE
#undef A_ISSUE

    // ---- once-per-block stats reduce: shuffle (quads) -> LDS (waves,
    //      reusing dead sBH) -> 2 global atomics per column per block
    #pragma unroll
    for (int j = 0; j < NJ; j++) {
        stS[j] += __shfl_xor(stS[j], 16); stS[j] += __shfl_xor(stS[j], 32);
        stQ[j] += __shfl_xor(stQ[j], 16); stQ[j] += __shfl_xor(stQ[j], 32);
    }
    __syncthreads();                       // all K-loop reads of sBH done
    float* red = (float*)sBH;              // [8][COLS]: per-wave {S,Q} rows
    if (quad == 0) {
        #pragma unroll
        for (int j = 0; j < NJ; j++) {
            const int colL = j * 16 + rowL;
            red[(wv * 2 + 0) * COLS + colL] = stS[j];
            red[(wv * 2 + 1) * COLS + colL] = stQ[j];
        }
    }
    __syncthreads();
    if (tid < COLS) {
        float s = red[0 * COLS + tid] + red[2 * COLS + tid] +
                  red[4 * COLS + tid] + red[6 * COLS + tid];
        float q = red[1 * COLS + tid] + red[3 * COLS + tid] +
                  red[5 * COLS + tid] + red[7 * COLS + tid];
        atomicAdd(&colsum[n0 + tid], s);
        atomicAdd(&colsumsq[n0 + tid], q);
    }
}

// ===========================================================================
// Final outer BN (no relu) reading the bf16 y2 plane (y2 fp32 eliminated;
// bf16 rounding before the affine adds ~2^-9 relative — negligible).
// ===========================================================================
__global__ __launch_bounds__(256) void bn_out(
    const __bf16* __restrict__ y2b, const float* __restrict__ csIn,
    const float* __restrict__ cqIn, const float* __restrict__ gamma,
    const float* __restrict__ beta, float* __restrict__ out)
{
    __shared__ float scs[DIM], shs[DIM];
    if (threadIdx.x < DIM) {
        int c = threadIdx.x;
        float mu = csIn[c] * INVN;
        float var = cqIn[c] * INVN - mu * mu;
        float sv = gamma[c] * rsqrtf(var + BN_EPS);
        scs[c] = sv; shs[c] = beta[c] - mu * sv;
    }
    __syncthreads();
    int i = blockIdx.x * 256 + threadIdx.x;
    if (i >= NNODES * 32) return;
    int c = (i & 31) * 4;
    bf16x4v v4 = *(const bf16x4v*)&y2b[(size_t)i * 4];
    float4 s = *(const float4*)&scs[c];
    float4 t = *(const float4*)&shs[c];
    float4 o;
    o.x = (float)v4[0] * s.x + t.x;
    o.y = (float)v4[1] * s.y + t.y;
    o.z = (float)v4[2] * s.z + t.z;
    o.w = (float)v4[3] * s.w + t.w;
    *(float4*)&out[(size_t)i * 4] = o;
}

extern "C" void kernel_launch(void* const* d_in, const int* in_sizes, int n_in,
                              void* d_out, int out_size, void* d_ws, size_t ws_size,
                              hipStream_t stream)
{
    const float* x    = (const float*)d_in[0];
    const int*   ei   = (const int*)d_in[1];
    const int*   ea   = (const int*)d_in[2];
    const float* W1   = (const float*)d_in[3];
    const float* b1   = (const float*)d_in[4];
    const float* g1   = (const float*)d_in[5];
    const float* bb1  = (const float*)d_in[6];
    const float* W2   = (const float*)d_in[7];
    const float* b2   = (const float*)d_in[8];
    const float* epsv = (const float*)d_in[9];
    const float* bond = (const float*)d_in[10];
    const float* g2   = (const float*)d_in[11];
    const float* bb2  = (const float*)d_in[12];
    float* out = (float*)d_out;

    const int* src = ei;
    const int* dstp = ei + NEDGES;

    // ---- workspace layout (y2 fp32 slot retained but unused)
    float* ws = (float*)d_ws;
    float* y1F   = ws + (size_t)MPAD * DIM;       // reused: y1b bf16 plane
    float* stats = y1F + (size_t)MPAD * HID;      // 2 sets x 768
    __bf16* y1b  = (__bf16*)y1F;                  // MPAD*HID bf16
    __bf16* zH   = (__bf16*)(stats + 2 * 768);
    __bf16* zL   = zH + (size_t)MPAD * DIM;
    __bf16* bt1h = zL + (size_t)MPAD * DIM;
    __bf16* bt1l = bt1h + (size_t)NLAYERS * DIM * HID;
    __bf16* bt2h = bt1l + (size_t)NLAYERS * DIM * HID;
    __bf16* bt2l = bt2h + (size_t)NLAYERS * HID * DIM;
    int* iws     = (int*)(bt2l + (size_t)NLAYERS * HID * DIM);
    int* deg     = iws;                  // 50000
    int* cursor  = deg + NNODES;         // 50000
    int* row_ptr = cursor + NNODES;      // 50001
    int* partial = row_ptr + NNODES + 1; // 64
    int* epack   = partial + 64;         // NEDGES packed ints (region sized 2x)
    __bf16* y2b  = (__bf16*)(((uintptr_t)(epack + 2 * NEDGES) + 15) & ~(uintptr_t)15);  // MPAD*DIM bf16

    // ---- build CSR (dst-sorted packed edge list) + split weights, once
    hipMemsetAsync(deg, 0, 2 * NNODES * sizeof(int), stream);
    hist_kernel<<<(NEDGES + 255) / 256, 256, 0, stream>>>(dstp, deg);
    scan_sum<<<NCHUNK, 256, 0, stream>>>(deg, partial);
    scan_part<<<1, 64, 0, stream>>>(partial, NCHUNK, row_ptr + NNODES);
    scan_write<<<NCHUNK, 256, 0, stream>>>(deg, partial, row_ptr);
    scatter_kernel<<<(NEDGES + 255) / 256, 256, 0, stream>>>(
        src, dstp, ea, row_ptr, cursor, epack);
    wsplit_kernel<<<(2 * NLAYERS * DIM * HID + 255) / 256, 256, 0, stream>>>(
        W1, W2, bt1h, bt1l, bt2h, bt2l);

    for (int l = 0; l < NLAYERS; l++) {
        const int p = l & 1;
        float* cs1 = stats + p * 768;
        float* cq1 = cs1 + HID;
        float* cs2 = cq1 + HID;
        float* cq2 = cs2 + DIM;
        float* statsZ = stats + p * 768;   // whole set, zeroed by agg block 0

        if (l == 0) {
            agg_combine<0><<<(NNODES + 31) / 32, 1024, 0, stream>>>(
                x, nullptr, row_ptr, epack, bond + (size_t)l * BONDSZ * DIM,
                epsv, l, nullptr, nullptr, nullptr, nullptr, zH, zL, statsZ);
        } else {
            const int pp = (l - 1) & 1;
            float* pcs2 = stats + pp * 768 + 2 * HID;
            float* pcq2 = pcs2 + DIM;
            agg_combine<1><<<(NNODES + 31) / 32, 1024, 0, stream>>>(
                nullptr, y2b, row_ptr, epack, bond + (size_t)l * BONDSZ * DIM,
                epsv, l, pcs2, pcq2, g2 + (size_t)(l - 1) * DIM,
                bb2 + (size_t)(l - 1) * DIM, zH, zL, statsZ);
        }

        // gemm1: [MPAD x 128] @ [128 x 256] -> y1b (bf16)
        //   persistent: 1024 blocks (4/CU, 32.8KB LDS), COLS=64, XB=4,
        //   DEPTH=2, vmcnt(16)
        gemm_ps<DIM, HID, 64, 0, 4, 4, 2><<<1024, 256, 0, stream>>>(
            zH, zL, nullptr,
            bt1h + (size_t)l * HID * DIM, bt1l + (size_t)l * HID * DIM,
            b1 + (size_t)l * HID, nullptr, nullptr, nullptr, nullptr,
            y1b, cs1, cq1);

        // gemm2: [MPAD x 256] @ [256 x 128] -> y2b (bf16 only)
        //   persistent: 512 blocks (2/CU, 66KB LDS), COLS=64, XB=2,
        //   DEPTH=3, vmcnt(32)
        gemm_ps<HID, DIM, 64, 1, 2, 2, 3><<<512, 256, 0, stream>>>(
            nullptr, nullptr, y1b,
            bt2h + (size_t)l * DIM * HID, bt2l + (size_t)l * DIM * HID,
            b2 + (size_t)l * DIM, cs1, cq1, g1 + (size_t)l * HID,
            bb1 + (size_t)l * HID, y2b, cs2, cq2);
    }

    // final outer BN (layer 4 -> parity 0), no relu — reads bf16 plane
    {
        float* cs2 = stats + 0 * 768 + 2 * HID;
        float* cq2 = cs2 + DIM;
        bn_out<<<(NNODES * 32 + 255) / 256, 256, 0, stream>>>(
            y2b, cs2, cq2, g2 + (size_t)4 * DIM, bb2 + (size_t)4 * DIM, out);
    }
}

// Round 15
// 542.480 us; speedup vs baseline: 1.0512x; 1.0512x over previous
//
#include <hip/hip_runtime.h>
#include <hip/hip_bf16.h>

// Problem constants (fixed by the reference: N=50000, E=400000, D=128, H=256, L=5)
#define NNODES 50000
#define MPAD 50048          // 782 * 64 (gemm row padding)
#define NEDGES 400000
#define DIM 128
#define HID 256
#define NLAYERS 5
#define BONDSZ 13
#define NCOMBO 60           // 5*6*2 bond-attr combinations
#define BN_EPS 1e-5f
#define NCHUNK 49           // ceil(50000/1024)
#define INVN (1.0f / 50000.0f)

typedef __bf16 bf16x8 __attribute__((ext_vector_type(8)));
typedef __bf16 bf16x4v __attribute__((ext_vector_type(4)));
typedef float f32x4 __attribute__((ext_vector_type(4)));

// Inline-asm 16B global load: cannot be sunk by regalloc; dest stays live
// from issue to use. "memory" clobber orders C++ stores after it, which the
// persistent-loop vmcnt accounting relies on.
#define GLOAD16(dst, addr) \
    asm volatile("global_load_dwordx4 %0, %1, off" : "=v"(dst) : "v"(addr) : "memory")

// Counted wait (T4): never drain vmcnt to 0 in the stripe loop.
// gemm1 (DEPTH=2, 4 loads/stripe): at wait, outstanding = loads(t) 4 +
//   stores(t-1) 16 -> vmcnt(16) retires loads(t).
// gemm2 (DEPTH=3, 8 loads/stripe): wait vmcnt(32) AFTER issuing A(t+2):
//   newest 32 = loads(t+1) 8 + loads(t+2) 8 + stores(t-1) 16 -> loads(t)
//   older -> retired.
template<int N> __device__ __forceinline__ void vmwaitN() {
    if constexpr (N == 16)      asm volatile("s_waitcnt vmcnt(16)" ::: "memory");
    else if constexpr (N == 32) asm volatile("s_waitcnt vmcnt(32)" ::: "memory");
    else static_assert(N == 16 || N == 32, "unsupported vmcnt");
    __builtin_amdgcn_sched_barrier(0);
}

// ===========================================================================
// CSR build (once per call — edge topology is layer-invariant)
// ===========================================================================
__global__ __launch_bounds__(256) void hist_kernel(
    const int* __restrict__ dst, int* __restrict__ deg)
{
    int e = blockIdx.x * 256 + threadIdx.x;
    if (e < NEDGES) atomicAdd(&deg[dst[e]], 1);
}

__global__ __launch_bounds__(256) void scan_sum(
    const int* __restrict__ deg, int* __restrict__ partial)
{
    __shared__ int red[256];
    int base = blockIdx.x * 1024;
    int s = 0;
    for (int i = threadIdx.x; i < 1024; i += 256) {
        int idx = base + i;
        if (idx < NNODES) s += deg[idx];
    }
    red[threadIdx.x] = s;
    __syncthreads();
    for (int off = 128; off > 0; off >>= 1) {
        if (threadIdx.x < off) red[threadIdx.x] += red[threadIdx.x + off];
        __syncthreads();
    }
    if (threadIdx.x == 0) partial[blockIdx.x] = red[0];
}

__global__ void scan_part(int* __restrict__ partial, int n, int* __restrict__ rowptr_last)
{
    if (threadIdx.x == 0) {
        int acc = 0;
        for (int i = 0; i < n; i++) { int v = partial[i]; partial[i] = acc; acc += v; }
        rowptr_last[0] = acc;
    }
}

__global__ __launch_bounds__(256) void scan_write(
    const int* __restrict__ deg, const int* __restrict__ partial,
    int* __restrict__ row_ptr)
{
    __shared__ int red[256];
    int base = blockIdx.x * 1024;
    int t = threadIdx.x;
    int v[4];
    int s = 0;
    #pragma unroll
    for (int j = 0; j < 4; j++) {
        int idx = base + t * 4 + j;
        v[j] = (idx < NNODES) ? deg[idx] : 0;
        s += v[j];
    }
    red[t] = s;
    __syncthreads();
    for (int off = 1; off < 256; off <<= 1) {
        int x = (t >= off) ? red[t - off] : 0;
        __syncthreads();
        red[t] += x;
        __syncthreads();
    }
    int ex = red[t] - s + partial[blockIdx.x];
    #pragma unroll
    for (int j = 0; j < 4; j++) {
        int idx = base + t * 4 + j;
        if (idx < NNODES) row_ptr[idx] = ex;
        ex += v[j];
    }
}

// packed edge: (src << 6) | combo  (src < 2^17, combo < 60)
__global__ __launch_bounds__(256) void scatter_kernel(
    const int* __restrict__ src, const int* __restrict__ dst,
    const int* __restrict__ eattr, const int* __restrict__ row_ptr,
    int* __restrict__ cursor, int* __restrict__ epack)
{
    int e = blockIdx.x * 256 + threadIdx.x;
    if (e >= NEDGES) return;
    int d = dst[e];
    int pos = row_ptr[d] + atomicAdd(&cursor[d], 1);
    int a0 = eattr[e * 3 + 0];
    int a1 = eattr[e * 3 + 1];
    int a2 = eattr[e * 3 + 2];
    epack[pos] = (src[e] << 6) | (a0 * 12 + a1 * 2 + a2);
}

// ===========================================================================
// Weight pre-split (once): W -> transposed [n][k] bf16 hi/lo planes
// ===========================================================================
__global__ __launch_bounds__(256) void wsplit_kernel(
    const float* __restrict__ W1, const float* __restrict__ W2,
    __bf16* __restrict__ bt1h, __bf16* __restrict__ bt1l,
    __bf16* __restrict__ bt2h, __bf16* __restrict__ bt2l)
{
    int gid = blockIdx.x * 256 + threadIdx.x;
    const int total1 = NLAYERS * DIM * HID;
    if (gid < total1) {
        int n = gid % HID; int k = (gid / HID) % DIM; int l = gid / (DIM * HID);
        float w = W1[gid];
        __bf16 hi = (__bf16)w;
        int o = (l * HID + n) * DIM + k;
        bt1h[o] = hi; bt1l[o] = (__bf16)(w - (float)hi);
    } else {
        int g = gid - total1;
        if (g < NLAYERS * HID * DIM) {
            int n = g % DIM; int k = (g / DIM) % HID; int l = g / (HID * DIM);
            float w = W2[g];
            __bf16 hi = (__bf16)w;
            int o = (l * DIM + n) * HID + k;
            bt2h[o] = hi; bt2l[o] = (__bf16)(w - (float)hi);
        }
    }
}

// ===========================================================================
// Aggregation + GIN combine (CSR, zero atomics).
//   Round 15: z written as a SINGLE bf16 plane (was split hi/lo). z feeds
//   Linear1 -> BN, which renormalizes, so the 2^-9 relative truncation is
//   the same class as the y1b/y2b truncations already present. Halves
//   agg's write (25.6 -> 12.8MB) and gemm1's A fetch.
//   agg is otherwise at its structural floor: FETCH ~99MB = 8 XCDs x
//   ~12.5MB compulsory random-gather replication; outstanding-gather
//   arithmetic shows BW-bound (not latency), dur ~43.5us invariant.
// ===========================================================================
template<int TRANS>
__global__ __launch_bounds__(1024) void agg_combine(
    const float* __restrict__ hin,
    const __bf16* __restrict__ hb,
    const int* __restrict__ row_ptr, const int* __restrict__ epack,
    const float* __restrict__ bond,
    const float* __restrict__ epsv, int lidx,
    const float* __restrict__ csIn, const float* __restrict__ cqIn,
    const float* __restrict__ gamma, const float* __restrict__ beta,
    __bf16* __restrict__ zB,
    float* __restrict__ statsZero)
{
    __shared__ float T[BONDSZ * DIM];
    __shared__ float TC[NCOMBO * DIM];
    __shared__ float scs[DIM], shs[DIM];

    for (int i = threadIdx.x; i < BONDSZ * DIM; i += 1024) T[i] = bond[i];
    if (TRANS && threadIdx.x < DIM) {
        int c = threadIdx.x;
        float mu = csIn[c] * INVN;
        float var = cqIn[c] * INVN - mu * mu;
        float sv = gamma[c] * rsqrtf(var + BN_EPS);
        scs[c] = sv; shs[c] = beta[c] - mu * sv;
    }
    if (blockIdx.x == 0 && threadIdx.x < 768) statsZero[threadIdx.x] = 0.f;
    __syncthreads();
    // build combined table: TC[cb] = T[a0] + T[5+a1] + T[11+a2]
    for (int i = threadIdx.x; i < NCOMBO * DIM; i += 1024) {
        int cb = i >> 7, c = i & 127;
        int a0 = cb / 12, r = cb - a0 * 12;
        TC[i] = T[a0 * DIM + c] + T[(5 + (r >> 1)) * DIM + c] + T[(11 + (r & 1)) * DIM + c];
    }
    __syncthreads();

    const int wv = threadIdx.x >> 6;            // 0..15
    const int half = (threadIdx.x >> 5) & 1;
    const int li = threadIdx.x & 31;
    const int node = blockIdx.x * 32 + wv * 2 + half;
    if (node >= NNODES) return;
    const int f = li * 4;

    float4 sc4 = make_float4(1.f, 1.f, 1.f, 1.f);
    float4 sh4 = make_float4(0.f, 0.f, 0.f, 0.f);
    if (TRANS) { sc4 = *(const float4*)&scs[f]; sh4 = *(const float4*)&shs[f]; }

    float ax = 0.f, ay = 0.f, az = 0.f, aw = 0.f;
    const int s = row_ptr[node];
    const int e2 = row_ptr[node + 1];
    int i = s;
    // ---- 4-deep pipelined main loop
    for (; i + 3 < e2; i += 4) {
        int ev[4];
        ev[0] = epack[i];     ev[1] = epack[i + 1];
        ev[2] = epack[i + 2]; ev[3] = epack[i + 3];
        float4 gv[4], tv[4];
        #pragma unroll
        for (int u = 0; u < 4; u++) {
            if (TRANS) {
                bf16x4v gb = *(const bf16x4v*)&hb[(size_t)(ev[u] >> 6) * DIM + f];
                gv[u] = make_float4((float)gb[0], (float)gb[1], (float)gb[2], (float)gb[3]);
            } else {
                gv[u] = *(const float4*)&hin[(size_t)(ev[u] >> 6) * DIM + f];
            }
            tv[u] = *(const float4*)&TC[(ev[u] & 63) * DIM + f];
        }
        #pragma unroll
        for (int u = 0; u < 4; u++) {
            float4 g = gv[u], t = tv[u];
            if (TRANS) {
                g.x = fmaxf(g.x * sc4.x + sh4.x, 0.f); g.y = fmaxf(g.y * sc4.y + sh4.y, 0.f);
                g.z = fmaxf(g.z * sc4.z + sh4.z, 0.f); g.w = fmaxf(g.w * sc4.w + sh4.w, 0.f);
            }
            ax += fmaxf(g.x + t.x, 0.f);
            ay += fmaxf(g.y + t.y, 0.f);
            az += fmaxf(g.z + t.z, 0.f);
            aw += fmaxf(g.w + t.w, 0.f);
        }
    }
    // ---- tail (<=3 edges)
    for (; i < e2; i++) {
        int ev = epack[i];
        float4 g;
        if (TRANS) {
            bf16x4v gb = *(const bf16x4v*)&hb[(size_t)(ev >> 6) * DIM + f];
            g = make_float4((float)gb[0], (float)gb[1], (float)gb[2], (float)gb[3]);
        } else {
            g = *(const float4*)&hin[(size_t)(ev >> 6) * DIM + f];
        }
        float4 t = *(const float4*)&TC[(ev & 63) * DIM + f];
        if (TRANS) {
            g.x = fmaxf(g.x * sc4.x + sh4.x, 0.f); g.y = fmaxf(g.y * sc4.y + sh4.y, 0.f);
            g.z = fmaxf(g.z * sc4.z + sh4.z, 0.f); g.w = fmaxf(g.w * sc4.w + sh4.w, 0.f);
        }
        ax += fmaxf(g.x + t.x, 0.f);
        ay += fmaxf(g.y + t.y, 0.f);
        az += fmaxf(g.z + t.z, 0.f);
        aw += fmaxf(g.w + t.w, 0.f);
    }
    // ---- self term (bf16 plane for TRANS=1 — same class as messages)
    float4 hv;
    if (TRANS) {
        bf16x4v hbv = *(const bf16x4v*)&hb[(size_t)node * DIM + f];
        hv = make_float4((float)hbv[0], (float)hbv[1], (float)hbv[2], (float)hbv[3]);
        hv.x = fmaxf(hv.x * sc4.x + sh4.x, 0.f); hv.y = fmaxf(hv.y * sc4.y + sh4.y, 0.f);
        hv.z = fmaxf(hv.z * sc4.z + sh4.z, 0.f); hv.w = fmaxf(hv.w * sc4.w + sh4.w, 0.f);
    } else {
        hv = *(const float4*)&hin[(size_t)node * DIM + f];
    }
    float ep = 1.0f + epsv[lidx];
    float z0 = ep * hv.x + ax, z1 = ep * hv.y + ay;
    float z2 = ep * hv.z + az, z3 = ep * hv.w + aw;
    size_t o = (size_t)node * DIM + f;
    bf16x4v vh = {(__bf16)z0, (__bf16)z1, (__bf16)z2, (__bf16)z3};
    *(bf16x4v*)(zB + o) = vh;
}

// ===========================================================================
// PERSISTENT-STRIPE split-precision MFMA GEMM (round 15).
//   Structure: B staged once (both planes, hi+lo weight split retained);
//   stripe t+1's asm loads in flight across stripe t's compute; stats in
//   registers with one block reduce through dead sBH; XCD stripe pairing;
//   all outputs bf16.
//   TRANSFORM=0 (gemm1): A = single bf16 z plane -> NK loads/stripe,
//     2 MFMAs per kstep-col (aH x bH, aH x bL). DEPTH=2, vmcnt(16).
//   TRANSFORM=1 (gemm2): A = bf16 y1b; BN+ReLU in fp32 at consume, split
//     hi/lo -> 3 MFMAs. DEPTH=3, vmcnt(32).
// ===========================================================================
template<int K, int NCOLS, int COLS, int TRANSFORM, int XB, int MINW, int DEPTH>
__global__ __launch_bounds__(256, MINW) void gemm_ps(
    const __bf16* __restrict__ AB,
    const __bf16* __restrict__ BTH, const __bf16* __restrict__ BTL,
    const float* __restrict__ bias,
    const float* __restrict__ csIn, const float* __restrict__ cqIn,
    const float* __restrict__ gamma, const float* __restrict__ beta,
    __bf16* __restrict__ outB,
    float* __restrict__ colsum, float* __restrict__ colsumsq)
{
    constexpr int KC  = K / 8;          // 16B chunks per col
    constexpr int NK  = K / 32;         // ksteps (gemm1 4, gemm2 8)
    constexpr int NJ  = COLS / 16;      // col sub-blocks per wave
    constexpr int NYB = MPAD / 64;      // 782 row-stripes of 64
    constexpr int WC  = (DEPTH == 3) ? 32 : 16;   // consume-wait count

    __shared__ __bf16 sBH[COLS * K], sBL[COLS * K];
    __shared__ float scs[TRANSFORM ? K : 1], shs[TRANSFORM ? K : 1];

    const int bid  = blockIdx.x;
    const int xcd  = bid & 7;
    const int grp  = bid >> 3;
    const int xb   = grp % XB;                      // column block
    const int pb   = (grp / XB) * 8 + xcd;          // stripe base 0..255
    const int tid  = threadIdx.x;
    const int lane = tid & 63;
    const int wv   = tid >> 6;
    const int rowL = lane & 15;
    const int quad = lane >> 4;
    const int n0   = xb * COLS;

    // A prefetch ring (depth DEPTH), stripe t uses buf t%DEPTH
    bf16x8 pA[DEPTH][NK];

#define A_ISSUE(tt) do {                                                      \
    const size_t rb_ = ((size_t)(pb + 256 * (tt)) * 64 + wv * 16 + rowL) * K  \
                       + quad * 8;                                            \
    _Pragma("unroll")                                                         \
    for (int ks = 0; ks < NK; ks++)                                           \
        GLOAD16(pA[(tt) % DEPTH][ks], AB + rb_ + ks * 32);                    \
} while (0)

    // prologue loads overlap the B staging phase (drained at the barrier)
    A_ISSUE(0);
    if constexpr (DEPTH == 3) {
        if (pb + 256 < NYB) A_ISSUE(1);
    }

    // per-block constants (keep ALL C++ global loads out of the stripe loop)
    float bb[NJ];
    #pragma unroll
    for (int j = 0; j < NJ; j++) bb[j] = bias[n0 + j * 16 + rowL];
    if (TRANSFORM) {
        for (int c = tid; c < K; c += 256) {
            float mu = csIn[c] * INVN;
            float var = cqIn[c] * INVN - mu * mu;
            float sv = gamma[c] * rsqrtf(var + BN_EPS);
            scs[c] = sv; shs[c] = beta[c] - mu * sv;
        }
    }

    // ---- stage B once (both planes, swizzled chunk layout)
    #pragma unroll
    for (int it = 0; it < (COLS * KC) / 256; it++) {
        int c = it * 256 + tid;
        int col = c / KC, kq = c % KC;
        int slot = col * KC + (kq ^ (col & (KC - 1)));
        size_t g = (size_t)(n0 + col) * K + kq * 8;
        *(bf16x8*)(sBH + slot * 8) = *(const bf16x8*)(BTH + g);
        *(bf16x8*)(sBL + slot * 8) = *(const bf16x8*)(BTL + g);
    }
    __syncthreads();                      // drains vmcnt incl. prologue loads
    __builtin_amdgcn_sched_barrier(0);

    // per-column stats accumulated in registers across stripes
    float stS[NJ] = {}, stQ[NJ] = {};

#define STRIPE(tt) do {                                                       \
    if (pb + 256 * (tt) < NYB) {                                              \
        if constexpr (DEPTH == 3 && (tt) + 2 <= 3) {                          \
            if (pb + 256 * ((tt) + 2) < NYB) A_ISSUE((tt) + 2);               \
        }                                                                     \
        if constexpr ((tt) > 0) { vmwaitN<WC>(); }                            \
        if constexpr (DEPTH == 2 && (tt) + 1 <= 3) {                          \
            if (pb + 256 * ((tt) + 1) < NYB) A_ISSUE((tt) + 1);               \
        }                                                                     \
        f32x4 acc[NJ] = {};                                                   \
        _Pragma("unroll")                                                     \
        for (int ks = 0; ks < NK; ks++) {                                     \
            bf16x8 aH8, aL8;                                                  \
            if constexpr (!TRANSFORM) {                                       \
                aH8 = pA[(tt) % DEPTH][ks];                                   \
            } else {                                                          \
                const int kb = ks * 32 + quad * 8;                            \
                float4 s0 = *(const float4*)&scs[kb];                         \
                float4 s1 = *(const float4*)&scs[kb + 4];                     \
                float4 t0 = *(const float4*)&shs[kb];                         \
                float4 t1 = *(const float4*)&shs[kb + 4];                     \
                float sv[8] = {s0.x, s0.y, s0.z, s0.w, s1.x, s1.y, s1.z, s1.w}; \
                float tv[8] = {t0.x, t0.y, t0.z, t0.w, t1.x, t1.y, t1.z, t1.w}; \
                _Pragma("unroll")                                             \
                for (int e = 0; e < 8; e++) {                                 \
                    float v = fmaxf((float)pA[(tt) % DEPTH][ks][e] * sv[e] + tv[e], 0.f); \
                    __bf16 hi = (__bf16)v;                                    \
                    aH8[e] = hi;                                              \
                    aL8[e] = (__bf16)(v - (float)hi);                         \
                }                                                             \
            }                                                                 \
            const int kqr = ks * 4 + quad;                                    \
            _Pragma("unroll")                                                 \
            for (int j = 0; j < NJ; j++) {                                    \
                int col = j * 16 + rowL;                                      \
                int slot = col * KC + (kqr ^ (col & (KC - 1)));               \
                bf16x8 bH = *(const bf16x8*)(sBH + slot * 8);                 \
                bf16x8 bL = *(const bf16x8*)(sBL + slot * 8);                 \
                acc[j] = __builtin_amdgcn_mfma_f32_16x16x32_bf16(aH8, bH, acc[j], 0, 0, 0); \
                if constexpr (TRANSFORM)                                      \
                    acc[j] = __builtin_amdgcn_mfma_f32_16x16x32_bf16(aL8, bH, acc[j], 0, 0, 0); \
                acc[j] = __builtin_amdgcn_mfma_f32_16x16x32_bf16(aH8, bL, acc[j], 0, 0, 0); \
            }                                                                 \
        }                                                                     \
        /* epilogue: exactly 16 unconditional bf16 stores (vmcnt accounting) */ \
        const int r0t = (pb + 256 * (tt)) * 64 + wv * 16 + quad * 4;          \
        _Pragma("unroll")                                                     \
        for (int j = 0; j < NJ; j++) {                                        \
            const int colL = j * 16 + rowL;                                   \
            _Pragma("unroll")                                                 \
            for (int r = 0; r < 4; r++) {                                     \
                const int rr = r0t + r;                                       \
                float v = acc[j][r] + bb[j];                                  \
                outB[(size_t)rr * NCOLS + n0 + colL] = (__bf16)v;             \
                if (rr < NNODES) { stS[j] += v; stQ[j] += v * v; }            \
            }                                                                 \
        }                                                                     \
    }                                                                         \
} while (0)

    STRIPE(0);
    STRIPE(1);
    STRIPE(2);
    STRIPE(3);

#undef STRIPE
#undef A_ISSUE

    // ---- once-per-block stats reduce: shuffle (quads) -> LDS (waves,
    //      reusing dead sBH) -> 2 global atomics per column per block
    #pragma unroll
    for (int j = 0; j < NJ; j++) {
        stS[j] += __shfl_xor(stS[j], 16); stS[j] += __shfl_xor(stS[j], 32);
        stQ[j] += __shfl_xor(stQ[j], 16); stQ[j] += __shfl_xor(stQ[j], 32);
    }
    __syncthreads();                       // all K-loop reads of sBH done
    float* red = (float*)sBH;              // [8][COLS]: per-wave {S,Q} rows
    if (quad == 0) {
        #pragma unroll
        for (int j = 0; j < NJ; j++) {
            const int colL = j * 16 + rowL;
            red[(wv * 2 + 0) * COLS + colL] = stS[j];
            red[(wv * 2 + 1) * COLS + colL] = stQ[j];
        }
    }
    __syncthreads();
    if (tid < COLS) {
        float s = red[0 * COLS + tid] + red[2 * COLS + tid] +
                  red[4 * COLS + tid] + red[6 * COLS + tid];
        float q = red[1 * COLS + tid] + red[3 * COLS + tid] +
                  red[5 * COLS + tid] + red[7 * COLS + tid];
        atomicAdd(&colsum[n0 + tid], s);
        atomicAdd(&colsumsq[n0 + tid], q);
    }
}

// ===========================================================================
// Final outer BN (no relu) reading the bf16 y2 plane.
// ===========================================================================
__global__ __launch_bounds__(256) void bn_out(
    const __bf16* __restrict__ y2b, const float* __restrict__ csIn,
    const float* __restrict__ cqIn, const float* __restrict__ gamma,
    const float* __restrict__ beta, float* __restrict__ out)
{
    __shared__ float scs[DIM], shs[DIM];
    if (threadIdx.x < DIM) {
        int c = threadIdx.x;
        float mu = csIn[c] * INVN;
        float var = cqIn[c] * INVN - mu * mu;
        float sv = gamma[c] * rsqrtf(var + BN_EPS);
        scs[c] = sv; shs[c] = beta[c] - mu * sv;
    }
    __syncthreads();
    int i = blockIdx.x * 256 + threadIdx.x;
    if (i >= NNODES * 32) return;
    int c = (i & 31) * 4;
    bf16x4v v4 = *(const bf16x4v*)&y2b[(size_t)i * 4];
    float4 s = *(const float4*)&scs[c];
    float4 t = *(const float4*)&shs[c];
    float4 o;
    o.x = (float)v4[0] * s.x + t.x;
    o.y = (float)v4[1] * s.y + t.y;
    o.z = (float)v4[2] * s.z + t.z;
    o.w = (float)v4[3] * s.w + t.w;
    *(float4*)&out[(size_t)i * 4] = o;
}

extern "C" void kernel_launch(void* const* d_in, const int* in_sizes, int n_in,
                              void* d_out, int out_size, void* d_ws, size_t ws_size,
                              hipStream_t stream)
{
    const float* x    = (const float*)d_in[0];
    const int*   ei   = (const int*)d_in[1];
    const int*   ea   = (const int*)d_in[2];
    const float* W1   = (const float*)d_in[3];
    const float* b1   = (const float*)d_in[4];
    const float* g1   = (const float*)d_in[5];
    const float* bb1  = (const float*)d_in[6];
    const float* W2   = (const float*)d_in[7];
    const float* b2   = (const float*)d_in[8];
    const float* epsv = (const float*)d_in[9];
    const float* bond = (const float*)d_in[10];
    const float* g2   = (const float*)d_in[11];
    const float* bb2  = (const float*)d_in[12];
    float* out = (float*)d_out;

    const int* src = ei;
    const int* dstp = ei + NEDGES;

    // ---- workspace layout (zL slot retained but unused)
    float* ws = (float*)d_ws;
    float* y1F   = ws + (size_t)MPAD * DIM;       // reused: y1b bf16 plane
    float* stats = y1F + (size_t)MPAD * HID;      // 2 sets x 768
    __bf16* y1b  = (__bf16*)y1F;                  // MPAD*HID bf16
    __bf16* zB   = (__bf16*)(stats + 2 * 768);    // MPAD*DIM bf16 (single plane)
    __bf16* zL_  = zB + (size_t)MPAD * DIM;       // unused (layout keeper)
    __bf16* bt1h = zL_ + (size_t)MPAD * DIM;
    __bf16* bt1l = bt1h + (size_t)NLAYERS * DIM * HID;
    __bf16* bt2h = bt1l + (size_t)NLAYERS * DIM * HID;
    __bf16* bt2l = bt2h + (size_t)NLAYERS * HID * DIM;
    int* iws     = (int*)(bt2l + (size_t)NLAYERS * HID * DIM);
    int* deg     = iws;                  // 50000
    int* cursor  = deg + NNODES;         // 50000
    int* row_ptr = cursor + NNODES;      // 50001
    int* partial = row_ptr + NNODES + 1; // 64
    int* epack   = partial + 64;         // NEDGES packed ints (region sized 2x)
    __bf16* y2b  = (__bf16*)(((uintptr_t)(epack + 2 * NEDGES) + 15) & ~(uintptr_t)15);  // MPAD*DIM bf16

    // ---- build CSR (dst-sorted packed edge list) + split weights, once
    hipMemsetAsync(deg, 0, 2 * NNODES * sizeof(int), stream);
    hist_kernel<<<(NEDGES + 255) / 256, 256, 0, stream>>>(dstp, deg);
    scan_sum<<<NCHUNK, 256, 0, stream>>>(deg, partial);
    scan_part<<<1, 64, 0, stream>>>(partial, NCHUNK, row_ptr + NNODES);
    scan_write<<<NCHUNK, 256, 0, stream>>>(deg, partial, row_ptr);
    scatter_kernel<<<(NEDGES + 255) / 256, 256, 0, stream>>>(
        src, dstp, ea, row_ptr, cursor, epack);
    wsplit_kernel<<<(2 * NLAYERS * DIM * HID + 255) / 256, 256, 0, stream>>>(
        W1, W2, bt1h, bt1l, bt2h, bt2l);

    for (int l = 0; l < NLAYERS; l++) {
        const int p = l & 1;
        float* cs1 = stats + p * 768;
        float* cq1 = cs1 + HID;
        float* cs2 = cq1 + HID;
        float* cq2 = cs2 + DIM;
        float* statsZ = stats + p * 768;   // whole set, zeroed by agg block 0

        if (l == 0) {
            agg_combine<0><<<(NNODES + 31) / 32, 1024, 0, stream>>>(
                x, nullptr, row_ptr, epack, bond + (size_t)l * BONDSZ * DIM,
                epsv, l, nullptr, nullptr, nullptr, nullptr, zB, statsZ);
        } else {
            const int pp = (l - 1) & 1;
            float* pcs2 = stats + pp * 768 + 2 * HID;
            float* pcq2 = pcs2 + DIM;
            agg_combine<1><<<(NNODES + 31) / 32, 1024, 0, stream>>>(
                nullptr, y2b, row_ptr, epack, bond + (size_t)l * BONDSZ * DIM,
                epsv, l, pcs2, pcq2, g2 + (size_t)(l - 1) * DIM,
                bb2 + (size_t)(l - 1) * DIM, zB, statsZ);
        }

        // gemm1: [MPAD x 128] @ [128 x 256] -> y1b (bf16)
        //   persistent: 1024 blocks (4/CU, 32.8KB LDS), COLS=64, XB=4,
        //   single-plane A (4 loads/stripe), DEPTH=2, vmcnt(16)
        gemm_ps<DIM, HID, 64, 0, 4, 4, 2><<<1024, 256, 0, stream>>>(
            zB,
            bt1h + (size_t)l * HID * DIM, bt1l + (size_t)l * HID * DIM,
            b1 + (size_t)l * HID, nullptr, nullptr, nullptr, nullptr,
            y1b, cs1, cq1);

        // gemm2: [MPAD x 256] @ [256 x 128] -> y2b (bf16)
        //   persistent: 512 blocks (2/CU, 66KB LDS), COLS=64, XB=2,
        //   DEPTH=3, vmcnt(32)
        gemm_ps<HID, DIM, 64, 1, 2, 2, 3><<<512, 256, 0, stream>>>(
            y1b,
            bt2h + (size_t)l * DIM * HID, bt2l + (size_t)l * DIM * HID,
            b2 + (size_t)l * DIM, cs1, cq1, g1 + (size_t)l * HID,
            bb1 + (size_t)l * HID, y2b, cs2, cq2);
    }

    // final outer BN (layer 4 -> parity 0), no relu — reads bf16 plane
    {
        float* cs2 = stats + 0 * 768 + 2 * HID;
        float* cq2 = cs2 + DIM;
        bn_out<<<(NNODES * 32 + 255) / 256, 256, 0, stream>>>(
            y2b, cs2, cq2, g2 + (size_t)4 * DIM, bb2 + (size_t)4 * DIM, out);
    }
}